// Round 3
// baseline (5671.666 us; speedup 1.0000x reference)
//
#include <hip/hip_runtime.h>

// RNN forward: out = tanh-scan(emb[x] @ W_xh + b_h ; W_hh) @ cls_w + cls_bias
// B=64, S=512, D=512, H=1024, O=32000. All fp32 in/out.
//
// Structure:
//   zero_ws   : zero sync flags + h exchange buffers (ws re-poisoned each call)
//   xw_gemm   : xw[s][b][:] = emb[x[b,s]] @ W_xh + b_h   (split-bf16 MFMA, [S][B][H] layout)
//   rnn_steps : PLAIN launch, 256 WGs (1/CU by 132KB-LDS capacity; grid == CU count;
//               __launch_bounds__(256,1)). 8 groups (8 batch rows each) x 32 slots
//               (32 H-cols each). W_hh slice pre-packed in LDS as split hi/lo bf16
//               MFMA fragments (loaded once, reused 512x).
//               Per step: BOUNDED poll of 32 per-slot flags (vector load + ballot,
//               20k-iter cap: protocol bug => wrong answer, never a hung container)
//               -> acquire fence -> plain uint4 loads of group h -> 48 MFMAs/wave
//               (split bf16: hh+hl+lh) -> LDS k-reduce -> tanh -> packed (hi,lo)
//               u32 agent-scope store -> barrier (drains vmcnt) -> flag store.
//               3 rotating h buffers; member lag <= 1 step => WAR-safe.
//   cls_gemm  : out = h_last @ cls_w + cls_bias (split-bf16 MFMA)
//
// Precision: recurrence has ~unit Lyapunov gain (xavier W_hh), so plain bf16
// would random-walk to ~4-10% output error over 512 steps. Split-bf16 (hi+lo,
// 3 MFMAs/product) gives ~1.5e-5/step -> fp32-quality at MFMA speed.
//
// ws layout (needs ~129 MB):
//   [0)            xw      f32 [512][64][1024]  134217728 B
//   [134217728)    h_last  f32 [64][1024]          262144 B
//   [134479872)    flags   int [8 groups][32]        1024 B
//   [134480896)    h_ex    u32 [3][64][1024]       786432 B   (hi<<16|lo bf16 pair)

typedef __attribute__((ext_vector_type(8))) short bf16x8;
typedef __attribute__((ext_vector_type(4))) float f32x4;

#define BATCH 64
#define SEQ   512
#define DIM   512
#define HID   1024
#define OUTN  32000

#define XW_OFF    0L
#define HLAST_OFF 134217728L
#define CNT_OFF   134479872L
#define HEX_OFF   134480896L
#define WS_NEED   135267328L

__device__ __forceinline__ unsigned short f2bf_rn(float f) {
  unsigned u = __builtin_bit_cast(unsigned, f);
  u += 0x7fffu + ((u >> 16) & 1u);
  return (unsigned short)(u >> 16);
}
__device__ __forceinline__ float bf2f(unsigned short h) {
  return __builtin_bit_cast(float, (unsigned)h << 16);
}
__device__ __forceinline__ f32x4 mfma16(bf16x8 a, bf16x8 b, f32x4 c) {
  return __builtin_amdgcn_mfma_f32_16x16x32_bf16(a, b, c, 0, 0, 0);
}

__global__ void zero_ws(unsigned int* p, int n) {
  int i = blockIdx.x * blockDim.x + threadIdx.x;
  if (i < n) p[i] = 0u;
}

// ---------------- xw = gather(emb, x) @ W_xh + b_h ----------------
// Tiles 128x128, BK=32 fp32. A,B staged as split hi/lo bf16 in LDS (stride 40 u16:
// 16B-aligned fragments, 2-way bank alias only). 4 waves, each 64x64 (4x4 frags).
__global__ __launch_bounds__(256) void xw_gemm(
    const int* __restrict__ x, const float* __restrict__ emb,
    const float* __restrict__ Wxh, const float* __restrict__ bh,
    float* __restrict__ xw) {
  __shared__ unsigned short a_hi[128][40], a_lo[128][40];
  __shared__ unsigned short b_hi[128][40], b_lo[128][40];
  const int tid = threadIdx.x;
  const int mt = blockIdx.x >> 3, nt = blockIdx.x & 7;  // consecutive blocks share A rows
  const int row0 = mt * 128, col0 = nt * 128;
  const int lane = tid & 63, wave = tid >> 6;
  const int wm = (wave >> 1) * 64, wn = (wave & 1) * 64;

  // A staging: thread -> (row, 16-elem k-half). row r=(s*64+b): b=r&63, s=r>>6.
  const int arow = tid >> 1;
  const int r = row0 + arow;
  const int token = x[(r & 63) * SEQ + (r >> 6)];
  const float* aptr = emb + (long)token * DIM + (tid & 1) * 16;
  const int akk = (tid & 1) * 16;
  // B staging: thread -> (k=tid>>3, 16-col block)
  const int bk = tid >> 3, bn = (tid & 7) * 16;
  const float* bptr = Wxh + (long)bk * HID + col0 + bn;

  f32x4 acc[4][4] = {};

  for (int k0 = 0; k0 < DIM; k0 += 32) {
    __syncthreads();
    {  // stage A (gathered emb rows), split hi/lo
      float v[16];
#pragma unroll
      for (int j = 0; j < 16; j += 4)
        *(float4*)&v[j] = *(const float4*)(aptr + k0 + j);
      bf16x8 vh0, vh1, vl0, vl1;
#pragma unroll
      for (int j = 0; j < 8; j++) {
        unsigned short hb = f2bf_rn(v[j]);
        vh0[j] = (short)hb; vl0[j] = (short)f2bf_rn(v[j] - bf2f(hb));
        unsigned short hb2 = f2bf_rn(v[j + 8]);
        vh1[j] = (short)hb2; vl1[j] = (short)f2bf_rn(v[j + 8] - bf2f(hb2));
      }
      *(bf16x8*)&a_hi[arow][akk] = vh0; *(bf16x8*)&a_hi[arow][akk + 8] = vh1;
      *(bf16x8*)&a_lo[arow][akk] = vl0; *(bf16x8*)&a_lo[arow][akk + 8] = vl1;
    }
    {  // stage B transposed [n][k] so frags are k-contiguous
      float v[16];
#pragma unroll
      for (int j = 0; j < 16; j += 4)
        *(float4*)&v[j] = *(const float4*)(bptr + (long)k0 * HID + j);
#pragma unroll
      for (int j = 0; j < 16; j++) {
        unsigned short hb = f2bf_rn(v[j]);
        b_hi[bn + j][bk] = hb;
        b_lo[bn + j][bk] = f2bf_rn(v[j] - bf2f(hb));
      }
    }
    __syncthreads();
    bf16x8 Ah[4], Al[4], Bh[4], Bl[4];
#pragma unroll
    for (int mi = 0; mi < 4; mi++) {
      Ah[mi] = *(const bf16x8*)&a_hi[wm + mi * 16 + (lane & 15)][(lane >> 4) * 8];
      Al[mi] = *(const bf16x8*)&a_lo[wm + mi * 16 + (lane & 15)][(lane >> 4) * 8];
    }
#pragma unroll
    for (int ni = 0; ni < 4; ni++) {
      Bh[ni] = *(const bf16x8*)&b_hi[wn + ni * 16 + (lane & 15)][(lane >> 4) * 8];
      Bl[ni] = *(const bf16x8*)&b_lo[wn + ni * 16 + (lane & 15)][(lane >> 4) * 8];
    }
#pragma unroll
    for (int mi = 0; mi < 4; mi++)
#pragma unroll
      for (int ni = 0; ni < 4; ni++) {
        acc[mi][ni] = mfma16(Ah[mi], Bh[ni], acc[mi][ni]);
        acc[mi][ni] = mfma16(Ah[mi], Bl[ni], acc[mi][ni]);
        acc[mi][ni] = mfma16(Al[mi], Bh[ni], acc[mi][ni]);
      }
  }
  // epilogue: + b_h, store fp32. C/D: col=lane&15, row=(lane>>4)*4+reg (m89-verified)
#pragma unroll
  for (int ni = 0; ni < 4; ni++) {
    const int c = col0 + wn + ni * 16 + (lane & 15);
    const float bias = bh[c];
#pragma unroll
    for (int mi = 0; mi < 4; mi++) {
      const int rb = row0 + wm + mi * 16 + (lane >> 4) * 4;
#pragma unroll
      for (int rr = 0; rr < 4; rr++)
        xw[(long)(rb + rr) * HID + c] = acc[mi][ni][rr] + bias;
    }
  }
}

// ---------------- recurrence ----------------
// Plain launch; co-residency by capacity: 132KB LDS => 1 WG/CU, grid=256=CU count.
__global__ __launch_bounds__(256, 1) void rnn_steps(
    const float* __restrict__ Whh, const float* __restrict__ xw,
    unsigned int* __restrict__ h_ex, int* __restrict__ flags_base,
    float* __restrict__ h_last) {
  extern __shared__ unsigned char smem[];
  unsigned short* wfrag = (unsigned short*)smem;  // [part2][nt2][ks32][lane64][e8] bf16
  float* red = (float*)(smem + 131072);           // [wave4*nt2][row8][col16] f32
  const int tid = threadIdx.x, lane = tid & 63, wave = tid >> 6;
  const int group = blockIdx.x & 7;   // batch rows [8g, 8g+8); blk&7 -> likely same XCD
  const int slot = blockIdx.x >> 3;   // H columns [32s, 32s+32)
  const int col0 = slot * 32;

  // ---- one-time: pack W_hh slice into fragment layout, split hi/lo ----
  for (int ks = wave; ks < 32; ks += 4) {
#pragma unroll
    for (int ntl = 0; ntl < 2; ntl++) {
      const int kbase = ks * 32 + (lane >> 4) * 8;
      const int col = col0 + ntl * 16 + (lane & 15);
      bf16x8 vh, vl;
#pragma unroll
      for (int e = 0; e < 8; e++) {
        float w = Whh[(long)(kbase + e) * HID + col];
        unsigned short hb = f2bf_rn(w);
        vh[e] = (short)hb;
        vl[e] = (short)f2bf_rn(w - bf2f(hb));
      }
      *(bf16x8*)&wfrag[(((0 * 2 + ntl) * 32 + ks) * 64 + lane) * 8] = vh;
      *(bf16x8*)&wfrag[(((1 * 2 + ntl) * 32 + ks) * 64 + lane) * 8] = vl;
    }
  }
  __syncthreads();

  int* flags = flags_base + group * 32;             // 32 per-slot flags, one 128B line
  const int erow = tid >> 5, ecol = tid & 31;       // epilogue: 1 output/thread
  const int b_glob = group * 8 + erow;
  const int arow = group * 8 + (lane & 7);          // A rows 8-15 duplicate 0-7 (discarded)

  for (int t = 1; t <= SEQ; t++) {
    // prefetch this step's xw (independent of h -> overlaps the poll)
    const float xw_v = xw[(long)((t - 1) * BATCH + b_glob) * HID + col0 + ecol];
    // wait until all 32 group members published h_{t-1}: one vector load + ballot.
    // BOUNDED: a protocol failure produces a wrong answer, never a hung container.
    const int target = t - 1;
    int spin = 0;
    for (;;) {
      const int v = __hip_atomic_load(flags + (lane & 31), __ATOMIC_RELAXED,
                                      __HIP_MEMORY_SCOPE_AGENT);
      if (__ballot(v >= target) == ~0ull) break;
      if (++spin > 20000) break;  // ~6ms cap; legit waits are <<1ms
      __builtin_amdgcn_s_sleep(1);
    }
    // producer data is at the coherence point (write-through atomic stores,
    // vmcnt-drained before its flag store); inv stale L1/L2 copies, then plain loads.
    __builtin_amdgcn_fence(__ATOMIC_ACQUIRE, "agent");

    const int rbuf = (t - 1) % 3;
    const uint4* hrow = (const uint4*)(h_ex + (long)(rbuf * BATCH + arow) * HID);
    uint4 hv[8][2];
#pragma unroll
    for (int kl = 0; kl < 8; kl++) {
      const int kb = ((wave * 8 + kl) * 32 + (lane >> 4) * 8) >> 2;  // uint4 units
      hv[kl][0] = hrow[kb];
      hv[kl][1] = hrow[kb + 1];
    }
    f32x4 acc0 = {}, acc1 = {};
#pragma unroll
    for (int kl = 0; kl < 8; kl++) {
      const int ks = wave * 8 + kl;
      const unsigned* hw = (const unsigned*)&hv[kl][0];
      bf16x8 ah, al;
#pragma unroll
      for (int e = 0; e < 8; e++) {
        ah[e] = (short)(hw[e] >> 16);
        al[e] = (short)(hw[e] & 0xffffu);
      }
      const bf16x8 bh0 = *(const bf16x8*)&wfrag[(((0) * 32 + ks) * 64 + lane) * 8];
      const bf16x8 bh1 = *(const bf16x8*)&wfrag[(((1) * 32 + ks) * 64 + lane) * 8];
      const bf16x8 bl0 = *(const bf16x8*)&wfrag[(((2) * 32 + ks) * 64 + lane) * 8];
      const bf16x8 bl1 = *(const bf16x8*)&wfrag[(((3) * 32 + ks) * 64 + lane) * 8];
      acc0 = mfma16(ah, bh0, acc0);
      acc0 = mfma16(ah, bl0, acc0);
      acc0 = mfma16(al, bh0, acc0);
      acc1 = mfma16(ah, bh1, acc1);
      acc1 = mfma16(ah, bl1, acc1);
      acc1 = mfma16(al, bh1, acc1);
    }
    // k-reduction across waves via LDS (rows 0-7 live in lanes 0-31)
    if (lane < 32) {
      const int rrow = (lane >> 4) * 4, rc = lane & 15;
#pragma unroll
      for (int rr = 0; rr < 4; rr++) {
        red[((wave * 2 + 0) * 8 + rrow + rr) * 16 + rc] = acc0[rr];
        red[((wave * 2 + 1) * 8 + rrow + rr) * 16 + rc] = acc1[rr];
      }
    }
    __syncthreads();
    float s = xw_v;
    const int nte = ecol >> 4, ce = ecol & 15;
#pragma unroll
    for (int w = 0; w < 4; w++) s += red[((w * 2 + nte) * 8 + erow) * 16 + ce];
    const float h = tanhf(s);
    const unsigned short hb = f2bf_rn(h);
    const unsigned short lb = f2bf_rn(h - bf2f(hb));
    const unsigned packed = ((unsigned)hb << 16) | (unsigned)lb;
    // agent-scope store: write-through to coherence point
    __hip_atomic_store(h_ex + (long)((t % 3) * BATCH + b_glob) * HID + col0 + ecol,
                       packed, __ATOMIC_RELAXED, __HIP_MEMORY_SCOPE_AGENT);
    if (t == SEQ) h_last[(long)b_glob * HID + col0 + ecol] = h;
    __syncthreads();  // compiler drains vmcnt(0) before s_barrier: all stores coherent
    if (tid == 0)
      __hip_atomic_store(flags + slot, t, __ATOMIC_RELAXED, __HIP_MEMORY_SCOPE_AGENT);
  }
}

// ---------------- out = h_last @ cls_w + cls_bias ----------------
__global__ __launch_bounds__(256) void cls_gemm(
    const float* __restrict__ h_last, const float* __restrict__ W,
    const float* __restrict__ bias, float* __restrict__ out) {
  __shared__ unsigned short a_hi[64][40], a_lo[64][40];
  __shared__ unsigned short b_hi[128][40], b_lo[128][40];
  const int tid = threadIdx.x, lane = tid & 63, wave = tid >> 6;
  const int n0 = blockIdx.x * 128;
  const int wn = wave * 32;
  const int sarow = tid >> 2, sak = (tid & 3) * 8;
  const int sbk = tid >> 3, sbn = (tid & 7) * 16;

  f32x4 acc[4][2] = {};
  for (int k0 = 0; k0 < HID; k0 += 32) {
    __syncthreads();
    {
      float v[8];
#pragma unroll
      for (int j = 0; j < 8; j += 4)
        *(float4*)&v[j] = *(const float4*)(h_last + (long)sarow * HID + k0 + sak + j);
      bf16x8 vh, vl;
#pragma unroll
      for (int j = 0; j < 8; j++) {
        unsigned short hb = f2bf_rn(v[j]);
        vh[j] = (short)hb; vl[j] = (short)f2bf_rn(v[j] - bf2f(hb));
      }
      *(bf16x8*)&a_hi[sarow][sak] = vh;
      *(bf16x8*)&a_lo[sarow][sak] = vl;
    }
    {
      float v[16];
#pragma unroll
      for (int j = 0; j < 16; j += 4)
        *(float4*)&v[j] = *(const float4*)(W + (long)(k0 + sbk) * OUTN + n0 + sbn + j);
#pragma unroll
      for (int j = 0; j < 16; j++) {
        unsigned short hb = f2bf_rn(v[j]);
        b_hi[sbn + j][sbk] = hb;
        b_lo[sbn + j][sbk] = f2bf_rn(v[j] - bf2f(hb));
      }
    }
    __syncthreads();
    bf16x8 Ah[4], Al[4], Bh[2], Bl[2];
#pragma unroll
    for (int mi = 0; mi < 4; mi++) {
      Ah[mi] = *(const bf16x8*)&a_hi[mi * 16 + (lane & 15)][(lane >> 4) * 8];
      Al[mi] = *(const bf16x8*)&a_lo[mi * 16 + (lane & 15)][(lane >> 4) * 8];
    }
#pragma unroll
    for (int ni = 0; ni < 2; ni++) {
      Bh[ni] = *(const bf16x8*)&b_hi[wn + ni * 16 + (lane & 15)][(lane >> 4) * 8];
      Bl[ni] = *(const bf16x8*)&b_lo[wn + ni * 16 + (lane & 15)][(lane >> 4) * 8];
    }
#pragma unroll
    for (int mi = 0; mi < 4; mi++)
#pragma unroll
      for (int ni = 0; ni < 2; ni++) {
        acc[mi][ni] = mfma16(Ah[mi], Bh[ni], acc[mi][ni]);
        acc[mi][ni] = mfma16(Ah[mi], Bl[ni], acc[mi][ni]);
        acc[mi][ni] = mfma16(Al[mi], Bh[ni], acc[mi][ni]);
      }
  }
#pragma unroll
  for (int ni = 0; ni < 2; ni++) {
    const int c = n0 + wn + ni * 16 + (lane & 15);
    const float bv = bias[c];
#pragma unroll
    for (int mi = 0; mi < 4; mi++) {
      const int rb = mi * 16 + (lane >> 4) * 4;
#pragma unroll
      for (int rr = 0; rr < 4; rr++)
        out[(long)(rb + rr) * OUTN + c] = acc[mi][ni][rr] + bv;
    }
  }
}

extern "C" void kernel_launch(void* const* d_in, const int* in_sizes, int n_in,
                              void* d_out, int out_size, void* d_ws, size_t ws_size,
                              hipStream_t stream) {
  const int* x = (const int*)d_in[0];
  const float* emb = (const float*)d_in[1];
  const float* Wxh = (const float*)d_in[2];
  const float* Whh = (const float*)d_in[3];
  const float* bh = (const float*)d_in[4];
  const float* clsw = (const float*)d_in[5];
  const float* clsb = (const float*)d_in[6];
  float* out = (float*)d_out;
  char* ws = (char*)d_ws;

  if (ws_size < (size_t)WS_NEED) return;  // leave output poisoned -> loud failure

  float* xw = (float*)(ws + XW_OFF);
  float* h_last = (float*)(ws + HLAST_OFF);
  int* flags = (int*)(ws + CNT_OFF);
  unsigned int* h_ex = (unsigned int*)(ws + HEX_OFF);

  // zero flags + h_ex (contiguous region)
  const int zn = (int)((WS_NEED - CNT_OFF) / 4);
  zero_ws<<<(zn + 255) / 256, 256, 0, stream>>>((unsigned int*)(ws + CNT_OFF), zn);

  xw_gemm<<<2048, 256, 0, stream>>>(x, emb, Wxh, bh, xw);

  (void)hipFuncSetAttribute(reinterpret_cast<const void*>(rnn_steps),
                            hipFuncAttributeMaxDynamicSharedMemorySize, 135168);
  rnn_steps<<<dim3(256), dim3(256), 135168, stream>>>(Whh, xw, h_ex, flags, h_last);

  cls_gemm<<<250, 256, 0, stream>>>(h_last, clsw, clsb, out);
}